// Round 10
// baseline (158.343 us; speedup 1.0000x reference)
//
#include <hip/hip_runtime.h>
#include <stdint.h>

// ENAS LSTM controller. R10 = R9's single-hop tagged exchange, PURE HIP:
// no inline asm, no XCC detection, no sc0 paths (prime suspects for R9's
// infra failure). Each wg publishes its y-partial (256 words: column-slice
// of w2@h or w1@h, computable from its OWN h-slice) plus its 32 h elements
// as self-validating (tag|k, f32) u64 words via relaxed agent-scope atomics
// (proven in R7/R8). Peers poll the DATA words directly -- one visibility
// hop, no atomicAdd RMW trains, no dependent second load. Each wg sums the
// 8 partials in a fixed order -> bitwise-identical y in all wgs -> local
// sampling stays consistent. Double-buffered exchange region; reuse safety
// from the phase-ordering invariant (publishing k+2 implies all peers
// finished polling k). LDS fixes vs R8: wave-uniform k-slice (broadcast dot
// reads, stride-1 gate reduce), stride-64 sample reads.
// ws need 221,696 B; falls back to the PROVEN R8 kernel if smaller.

#define NBLK  6
#define PWG   8
#define TINYF 1.17549435e-38f
#define XTAG  0xC3B00000u
#define DONE_MAGIC 0x444f4e45

typedef unsigned long long u64;
struct U2 { uint32_t x, y; };

// ---- v10 ws layout (bytes) ----
#define V10_DONE 0u        // int[8]
#define V10_PART 64u       // float[12]
#define V10_EX   512u      // u64 ex[2][6][8][288] = 221,184
#define V10_NEED 221696u

// ---- R8 fallback ws layout ----
#define S_READY 0u
#define S_DONE  192u
#define S_PART  224u
#define S_HP    320u
#define S_ACC   24896u
#define FXS     67108864.0f
#define READY_MAGIC 0x52454459

// Threefry-2x32, 20 rounds (Random123 / JAX). Key (k0,k1), counter (c0,c1).
__device__ __forceinline__ U2 tf2x32(uint32_t k0, uint32_t k1,
                                     uint32_t c0, uint32_t c1) {
  uint32_t ks2 = k0 ^ k1 ^ 0x1BD11BDAu;
  uint32_t x0 = c0 + k0, x1 = c1 + k1;
#define TFR(r) { x0 += x1; x1 = (x1 << (r)) | (x1 >> (32 - (r))); x1 ^= x0; }
  TFR(13) TFR(15) TFR(26) TFR(6)   x0 += k1;  x1 += ks2 + 1u;
  TFR(17) TFR(29) TFR(16) TFR(24)  x0 += ks2; x1 += k0 + 2u;
  TFR(13) TFR(15) TFR(26) TFR(6)   x0 += k0;  x1 += k1 + 3u;
  TFR(17) TFR(29) TFR(16) TFR(24)  x0 += k1;  x1 += ks2 + 4u;
  TFR(13) TFR(15) TFR(26) TFR(6)   x0 += ks2; x1 += k0 + 5u;
#undef TFR
  U2 r; r.x = x0; r.y = x1; return r;
}

__device__ __forceinline__ float sigf(float x) {
  return 1.0f / (1.0f + expf(-x));
}
// relaxed agent-scope (LLC-resolved) accessors -- the only sync primitives.
__device__ __forceinline__ void istore(int* p, int v) {
  __hip_atomic_store(p, v, __ATOMIC_RELAXED, __HIP_MEMORY_SCOPE_AGENT);
}
__device__ __forceinline__ int iload(const int* p) {
  return __hip_atomic_load(p, __ATOMIC_RELAXED, __HIP_MEMORY_SCOPE_AGENT);
}
__device__ __forceinline__ void hstore(u64* p, u64 v) {
  __hip_atomic_store(p, v, __ATOMIC_RELAXED, __HIP_MEMORY_SCOPE_AGENT);
}
__device__ __forceinline__ u64 hload(const u64* p) {
  return __hip_atomic_load(p, __ATOMIC_RELAXED, __HIP_MEMORY_SCOPE_AGENT);
}
__device__ __forceinline__ void fstore(float* p, float v) {
  __hip_atomic_store(p, v, __ATOMIC_RELAXED, __HIP_MEMORY_SCOPE_AGENT);
}
__device__ __forceinline__ float fload(const float* p) {
  return __hip_atomic_load(p, __ATOMIC_RELAXED, __HIP_MEMORY_SCOPE_AGENT);
}

// =================== R10 kernel (single-hop, pure HIP) =====================
__global__ __launch_bounds__(1024) void ctrl_v10(
    const float* __restrict__ enc_w,
    const float* __restrict__ wih,
    const float* __restrict__ whh,
    const float* __restrict__ b_ih,
    const float* __restrict__ b_hh,
    const float* __restrict__ w1,
    const float* __restrict__ w2,
    const float* __restrict__ vvec,
    unsigned char* __restrict__ ws,
    float* __restrict__ out) {

  const int b = blockIdx.x & 7;      // XCD swizzle: chain b -> XCD b (if RR)
  const int p = blockIdx.x >> 3;
  if (b >= NBLK) return;
  const int tid = threadIdx.x;

  int*   done = (int*)(ws + V10_DONE);
  float* part = (float*)(ws + V10_PART);
  u64*   ex   = (u64*)(ws + V10_EX);

  // gate GEMV: k-slice s wave-uniform (LDS broadcast), 128 local rows rl
  const int rl = tid & 127, s = tid >> 7;
  const int g = rl >> 5, el = rl & 31;
  const int row = g * 256 + p * 32 + el;
  const int k0 = s * 32;
  // y-partial: element rr, own-col chunk ks (cols p*32 + ks*8 + j)
  const int rr = tid & 255, ks = tid >> 8;

  __shared__ __align__(16) float gateL[1024];
  __shared__ __align__(16) float hL[256], encL[256], vL[256];
  __shared__ __align__(16) float anchL[4][256];
  __shared__ __align__(16) float w2hS[256], aw1S[6][256];
  __shared__ float rowSumL[128], biasS[128], h2S[32];
  __shared__ float logitL[8];
  __shared__ int   selL;

  if (tid < 256) { encL[tid] = enc_w[tid]; vL[tid] = vvec[tid]; }
  if (tid < 128) {
    int r = (tid >> 5) * 256 + p * 32 + (tid & 31);
    biasS[tid] = b_ih[r] + b_hh[r];
  }

  // register-resident weights
  float4 wihr[8], whhr[8];
  #pragma unroll
  for (int c = 0; c < 8; ++c) {
    int cc = (c + s) & 7;
    wihr[c] = *(const float4*)(wih + row * 256 + k0 + cc * 4);
    whhr[c] = *(const float4*)(whh + row * 256 + k0 + cc * 4);
  }
  float w1c[8], w2c[8];
  #pragma unroll
  for (int j = 0; j < 8; ++j) {
    w1c[j] = w1[rr * 256 + p * 32 + ks * 8 + j];
    w2c[j] = w2[rr * 256 + p * 32 + ks * 8 + j];
  }
  __syncthreads();

  auto dotIH = [&](const float* x) {
    float a = 0.0f;
    #pragma unroll
    for (int c = 0; c < 8; ++c) {
      int cc = (c + s) & 7;
      float4 xv = *(const float4*)(x + k0 + cc * 4);
      float4 w = wihr[c];
      a += w.x * xv.x + w.y * xv.y + w.z * xv.z + w.w * xv.w;
    }
    return a;
  };
  auto dotHH = [&]() {
    float a = 0.0f;
    #pragma unroll
    for (int c = 0; c < 8; ++c) {
      int cc = (c + s) & 7;
      float4 xv = *(const float4*)(hL + k0 + cc * 4);
      float4 w = whhr[c];
      a += w.x * xv.x + w.y * xv.y + w.z * xv.z + w.w * xv.w;
    }
    return a;
  };

  const float encih = dotIH(encL);   // wih @ enc, reused by all enc cells

  float cv = 0.0f;                            // c for element p*32+tid (tid<32)
  U2 bk = tf2x32(0u, 42u, 0u, (uint32_t)b);   // fold_in(key(42), b)
  int k = 1, step = 0;
  float lpAcc = 0.0f, entAcc = 0.0f;

  // One cell + single-hop exchange. mode 0: y=w2 partial -> w2hS;
  // mode 1: y=w1 partial -> aw1S[aid] (+ anchor -> anchL[cid] if cid>=0);
  // mode 2: last cell, no exchange.
  auto cell = [&](float gacc, int mode, int aid, int cid) {
    gateL[tid] = gacc;                       // tid = s*128 + rl
    __syncthreads();
    if (tid < 128) {                         // stride-128 reduce: 2-way free
      float ssum = 0.0f;
      #pragma unroll
      for (int j = 0; j < 8; ++j) ssum += gateL[j * 128 + tid];
      rowSumL[tid] = ssum + biasS[tid];
    }
    __syncthreads();
    if (tid < 32) {
      float gi = rowSumL[tid],       gf = rowSumL[32 + tid];
      float gg2 = rowSumL[64 + tid], go = rowSumL[96 + tid];
      float c2 = sigf(gf) * cv + sigf(gi) * tanhf(gg2);
      float h2 = sigf(go) * tanhf(c2);
      cv = c2;
      h2S[tid] = h2;
      if (mode == 2 && b == NBLK - 1) {
        out[62 + p * 32 + tid] = cv;
        out[318 + p * 32 + tid] = h2;
      }
    }
    __syncthreads();
    if (mode == 2) return;

    {                                        // own y partial (8 cols)
      const float* wc = (mode == 1) ? w1c : w2c;
      float yp = 0.0f;
      #pragma unroll
      for (int j = 0; j < 8; ++j) yp += wc[j] * h2S[ks * 8 + j];
      gateL[tid] = yp;                       // tid = ks*256 + rr
    }
    __syncthreads();
    const uint32_t tagk = XTAG | (uint32_t)k;
    u64* slot = ex + (((size_t)(k & 1) * NBLK + b) * PWG + p) * 288;
    if (tid < 256) {                         // publish y (fixed-order 4-sum)
      float yo = (gateL[tid] + gateL[256 + tid]) +
                 (gateL[512 + tid] + gateL[768 + tid]);
      hstore(slot + tid, ((u64)tagk << 32) | (u64)__float_as_uint(yo));
    } else if (tid < 288) {                  // publish h slice
      hstore(slot + tid,
             ((u64)tagk << 32) | (u64)__float_as_uint(h2S[tid - 256]));
    }
    __syncthreads();                         // gateL reuse protection
    {                                        // poll peers: up to 3 words, interleaved
      int e = tid & 255, q = tid >> 8;
      const u64* base = ex + (((size_t)(k & 1) * NBLK + b) * PWG) * 288;
      const u64* pa = base + (2 * q) * 288 + e;
      const u64* pb = base + (2 * q + 1) * 288 + e;
      const u64* ph = base + (tid >> 5) * 288 + 256 + (tid & 31);
      u64 va = 0, vb = 0, vh = 0;
      bool da = false, db = false, dh = (tid >= 256);
      for (;;) {
        if (!da) { va = hload(pa); da = ((uint32_t)(va >> 32) == tagk); }
        if (!db) { vb = hload(pb); db = ((uint32_t)(vb >> 32) == tagk); }
        if (!dh) { vh = hload(ph); dh = ((uint32_t)(vh >> 32) == tagk); }
        if (da && db && dh) break;
        __builtin_amdgcn_s_sleep(1);
      }
      gateL[tid] = __uint_as_float((uint32_t)va) +
                   __uint_as_float((uint32_t)vb);
      float hv = __uint_as_float((uint32_t)vh);
      __syncthreads();
      if (tid < 256) {
        float y = (gateL[tid] + gateL[256 + tid]) +
                  (gateL[512 + tid] + gateL[768 + tid]);
        if (mode == 1) aw1S[aid][tid] = y; else w2hS[tid] = y;
        hL[tid] = hv;
        if (mode == 1 && cid >= 0) anchL[cid][tid] = hv;
      }
    }
    __syncthreads();
    ++k;
  };

  // local sample: identical in every wg (bitwise-identical y/h inputs)
  auto sample = [&](int L) -> int {
    int wv = tid >> 6, lane = tid & 63;
    if (wv < L) {
      float a = 0.0f;
      #pragma unroll
      for (int j = 0; j < 4; ++j) {          // stride-64: conflict-free
        int kk = j * 64 + lane;
        a += tanhf(aw1S[wv][kk] + w2hS[kk]) * vL[kk];
      }
      a += __shfl_down(a, 32);
      a += __shfl_down(a, 16);
      a += __shfl_down(a, 8);
      a += __shfl_down(a, 4);
      a += __shfl_down(a, 2);
      a += __shfl_down(a, 1);
      if (lane == 0) logitL[wv] = a;
    }
    __syncthreads();
    if (tid < 64) {                          // wave 0: lane-parallel selection
      float lg = 0.0f, sgum = -1e30f;
      if (tid < L) {
        lg = 1.1f * tanhf(logitL[tid] * 0.2f);
        U2 sk = tf2x32(bk.x, bk.y, 0u, (uint32_t)step);
        U2 r2 = tf2x32(sk.x, sk.y, 0u, (uint32_t)tid);
        uint32_t bits = r2.x ^ r2.y;
        float u = __uint_as_float((bits >> 9) | 0x3f800000u) - 1.0f;
        u = fmaxf(TINYF, u + TINYF);         // jax uniform(tiny, 1)
        sgum = lg - logf(-logf(u));
      }
      int bi = 0;
      float best = __shfl(sgum, 0, 64);
      for (int j = 1; j < L; ++j) {
        float sj = __shfl(sgum, j, 64);
        if (sj > best) { best = sj; bi = j; }   // first-max = jnp.argmax
      }
      float mx = __shfl(lg, 0, 64);
      for (int j = 1; j < L; ++j) mx = fmaxf(mx, __shfl(lg, j, 64));
      float se = 0.0f;
      for (int j = 0; j < L; ++j) se += expf(__shfl(lg, j, 64) - mx);
      float lse = logf(se);
      float lgbi = __shfl(lg, bi, 64);
      float es = 0.0f;
      for (int j = 0; j < L; ++j) {
        float l = __shfl(lg, j, 64) - mx - lse;
        es += l * expf(l);
      }
      if (tid == 0) {
        lpAcc += -(lgbi - mx - lse);
        entAcc += -es;
        selL = bi;
        if (p == 0) out[b * 10 + step] = (float)bi;
      }
    }
    __syncthreads();
    step++;
    return selL;
  };

  // ---- chain ----
  cell(encih, 1, 0, -1);             // zero-state cell; publishes aw1[0]
  if (tid < 256) aw1S[1][tid] = aw1S[0][tid];
  __syncthreads();

  for (int L = 2; L <= 6; ++L) {
    cell(encih + dotHH(), 0, 0, -1);
    int s1v = sample(L);
    {
      float a = (s1v >= 2) ? dotIH(&anchL[s1v - 2][0]) : 0.0f;
      cell(a + dotHH(), 0, 0, -1);
    }
    int s2v = sample(L);
    {
      float a = (s2v >= 2) ? dotIH(&anchL[s2v - 2][0]) : 0.0f;
      if (L < 6) cell(a + dotHH(), 1, L, L - 2);
      else       cell(a + dotHH(), 2, 0, -1);
    }
  }

  if (p == 0 && tid == 0) {
    fstore(&part[2 * b], lpAcc);
    fstore(&part[2 * b + 1], entAcc);
    __builtin_amdgcn_s_waitcnt(0);
    istore(&done[b], DONE_MAGIC);
    if (b == NBLK - 1) {
      float lp = 0.0f, en = 0.0f;
      for (int j = 0; j < NBLK; ++j) {
        while (iload(&done[j]) != DONE_MAGIC) __builtin_amdgcn_s_sleep(1);
        lp += fload(&part[2 * j]);
        en += fload(&part[2 * j + 1]);
      }
      out[60] = lp;
      out[61] = en;
    }
  }
}

// =================== R8 fallback (proven; small ws) ========================
__global__ __launch_bounds__(1024) void ctrl_small(
    const float* __restrict__ enc_w,
    const float* __restrict__ wih,
    const float* __restrict__ whh,
    const float* __restrict__ b_ih,
    const float* __restrict__ b_hh,
    const float* __restrict__ w1,
    const float* __restrict__ w2,
    const float* __restrict__ vvec,
    unsigned char* __restrict__ ws,
    float* __restrict__ out) {

  const int b = blockIdx.x & 7;
  const int p = blockIdx.x >> 3;
  if (b >= NBLK) return;
  const int tid = threadIdx.x;

  int*   ready = (int*)(ws + S_READY);
  int*   done  = (int*)(ws + S_DONE);
  float* part  = (float*)(ws + S_PART);
  u64*   hp    = (u64*)(ws + S_HP);
  int*   acc   = (int*)(ws + S_ACC);

  const int rl = tid >> 3, s = tid & 7;
  const int g = rl >> 5, el = rl & 31;
  const int row = g * 256 + p * 32 + el;
  const int k0 = s * 32;
  const int rr = tid & 255, ks = tid >> 8;

  __shared__ __align__(16) float hL[256], encL[256], vL[256];
  __shared__ __align__(16) float anchL[4][256];
  __shared__ __align__(16) float partL[1024];
  __shared__ __align__(16) float w2hS[256], aw1S[6][256];
  __shared__ float rowSumL[128], biasS[128], h2S[32];
  __shared__ float logitL[8];
  __shared__ int   selL;

  if (tid < 256) { encL[tid] = enc_w[tid]; vL[tid] = vvec[tid]; }
  if (tid < 128) {
    int gg = tid >> 5, ee = tid & 31, r = gg * 256 + p * 32 + ee;
    biasS[tid] = b_ih[r] + b_hh[r];
  }

  float4 wihr[8], whhr[8];
  #pragma unroll
  for (int c = 0; c < 8; ++c) {
    int cc = (c + s) & 7;
    wihr[c] = *(const float4*)(wih + row * 256 + k0 + cc * 4);
    whhr[c] = *(const float4*)(whh + row * 256 + k0 + cc * 4);
  }
  float w1c[8], w2c[8];
  #pragma unroll
  for (int j = 0; j < 8; ++j) {
    w1c[j] = w1[rr * 256 + p * 32 + ks * 8 + j];
    w2c[j] = w2[rr * 256 + p * 32 + ks * 8 + j];
  }

  if (tid < 32) istore(&acc[1 * (NBLK * 256) + b * 256 + p * 32 + tid], 0);
  __syncthreads();
  if (tid == 0) istore(&ready[b * 8 + p], READY_MAGIC);
  if (tid < 8) {
    while (iload(&ready[b * 8 + tid]) != READY_MAGIC)
      __builtin_amdgcn_s_sleep(1);
  }
  __syncthreads();

  auto dotIH = [&](const float* x) {
    float a = 0.0f;
    #pragma unroll
    for (int c = 0; c < 8; ++c) {
      int cc = (c + s) & 7;
      float4 xv = *(const float4*)(x + k0 + cc * 4);
      float4 w = wihr[c];
      a += w.x * xv.x + w.y * xv.y + w.z * xv.z + w.w * xv.w;
    }
    return a;
  };
  auto dotHH = [&]() {
    float a = 0.0f;
    #pragma unroll
    for (int c = 0; c < 8; ++c) {
      int cc = (c + s) & 7;
      float4 xv = *(const float4*)(hL + k0 + cc * 4);
      float4 w = whhr[c];
      a += w.x * xv.x + w.y * xv.y + w.z * xv.z + w.w * xv.w;
    }
    return a;
  };

  const float encih = dotIH(encL);
  float cv = 0.0f;
  U2 bk = tf2x32(0u, 42u, 0u, (uint32_t)b);
  int k = 1, step = 0;
  float lpAcc = 0.0f, entAcc = 0.0f;

  auto cell = [&](float gacc, int mode, int aid, int cid) {
    partL[tid] = gacc;
    __syncthreads();
    if (tid < 128) {
      float ssum = 0.0f;
      #pragma unroll
      for (int j = 0; j < 8; ++j) ssum += partL[tid * 8 + j];
      rowSumL[tid] = ssum + biasS[tid];
    }
    __syncthreads();
    if (tid < 32) {
      float gi = rowSumL[tid],       gf = rowSumL[32 + tid];
      float gg2 = rowSumL[64 + tid], go = rowSumL[96 + tid];
      float c2 = sigf(gf) * cv + sigf(gi) * tanhf(gg2);
      float h2 = sigf(go) * tanhf(c2);
      cv = c2;
      h2S[tid] = h2;
      if (mode == 2 && b == NBLK - 1) {
        out[62 + p * 32 + tid] = cv;
        out[318 + p * 32 + tid] = h2;
      }
    }
    __syncthreads();
    if (mode == 2) return;
    {
      const float* wc = (mode == 1) ? w1c : w2c;
      float yp = 0.0f;
      #pragma unroll
      for (int j = 0; j < 8; ++j) yp += wc[j] * h2S[ks * 8 + j];
      atomicAdd(&acc[(k % 3) * (NBLK * 256) + b * 256 + rr],
                __float2int_rn(yp * FXS));
      if (tid < 32)
        istore(&acc[((k + 1) % 3) * (NBLK * 256) + b * 256 + p * 32 + tid], 0);
    }
    __syncthreads();
    if (tid < 32) {
      u64 pk = ((u64)(uint32_t)k << 32) | (u64)__float_as_uint(h2S[tid]);
      hstore(&hp[(k & 1) * (NBLK * 256) + b * 256 + p * 32 + tid], pk);
    }
    if (tid < 256) {
      u64 v;
      const u64* src = &hp[(k & 1) * (NBLK * 256) + b * 256 + tid];
      while ((int)(hload(src) >> 32) != k) __builtin_amdgcn_s_sleep(1);
      v = hload(src);
      float hv = __uint_as_float((uint32_t)v);
      hL[tid] = hv;
      if (mode == 1 && cid >= 0) anchL[cid][tid] = hv;
    }
    __syncthreads();
    if (tid < 256) {
      int iv = iload(&acc[(k % 3) * (NBLK * 256) + b * 256 + tid]);
      float f = (float)((double)iv * (1.0 / 67108864.0));
      if (mode == 1) aw1S[aid][tid] = f; else w2hS[tid] = f;
    }
    __syncthreads();
    ++k;
  };

  auto sample = [&](int L) -> int {
    int wv = tid >> 6, lane = tid & 63;
    if (wv < L) {
      float a = 0.0f;
      #pragma unroll
      for (int j = 0; j < 4; ++j) {
        int kk = lane * 4 + j;
        a += tanhf(aw1S[wv][kk] + w2hS[kk]) * vL[kk];
      }
      a += __shfl_down(a, 32);
      a += __shfl_down(a, 16);
      a += __shfl_down(a, 8);
      a += __shfl_down(a, 4);
      a += __shfl_down(a, 2);
      a += __shfl_down(a, 1);
      if (lane == 0) logitL[wv] = a;
    }
    __syncthreads();
    if (tid < 64) {
      float lg = 0.0f, sgum = -1e30f;
      if (tid < L) {
        lg = 1.1f * tanhf(logitL[tid] * 0.2f);
        U2 sk = tf2x32(bk.x, bk.y, 0u, (uint32_t)step);
        U2 r2 = tf2x32(sk.x, sk.y, 0u, (uint32_t)tid);
        uint32_t bits = r2.x ^ r2.y;
        float u = __uint_as_float((bits >> 9) | 0x3f800000u) - 1.0f;
        u = fmaxf(TINYF, u + TINYF);
        sgum = lg - logf(-logf(u));
      }
      int bi = 0;
      float best = __shfl(sgum, 0, 64);
      for (int j = 1; j < L; ++j) {
        float sj = __shfl(sgum, j, 64);
        if (sj > best) { best = sj; bi = j; }
      }
      float mx = __shfl(lg, 0, 64);
      for (int j = 1; j < L; ++j) mx = fmaxf(mx, __shfl(lg, j, 64));
      float se = 0.0f;
      for (int j = 0; j < L; ++j) se += expf(__shfl(lg, j, 64) - mx);
      float lse = logf(se);
      float lgbi = __shfl(lg, bi, 64);
      float es = 0.0f;
      for (int j = 0; j < L; ++j) {
        float l = __shfl(lg, j, 64) - mx - lse;
        es += l * expf(l);
      }
      if (tid == 0) {
        lpAcc += -(lgbi - mx - lse);
        entAcc += -es;
        selL = bi;
        if (p == 0) out[b * 10 + step] = (float)bi;
      }
    }
    __syncthreads();
    step++;
    return selL;
  };

  cell(encih, 1, 0, -1);
  if (tid < 256) aw1S[1][tid] = aw1S[0][tid];
  __syncthreads();
  for (int L = 2; L <= 6; ++L) {
    cell(encih + dotHH(), 0, 0, -1);
    int s1v = sample(L);
    {
      float a = (s1v >= 2) ? dotIH(&anchL[s1v - 2][0]) : 0.0f;
      cell(a + dotHH(), 0, 0, -1);
    }
    int s2v = sample(L);
    {
      float a = (s2v >= 2) ? dotIH(&anchL[s2v - 2][0]) : 0.0f;
      if (L < 6) cell(a + dotHH(), 1, L, L - 2);
      else       cell(a + dotHH(), 2, 0, -1);
    }
  }
  if (p == 0 && tid == 0) {
    fstore(&part[2 * b], lpAcc);
    fstore(&part[2 * b + 1], entAcc);
    __builtin_amdgcn_s_waitcnt(0);
    istore(&done[b], DONE_MAGIC);
    if (b == NBLK - 1) {
      float lp = 0.0f, en = 0.0f;
      for (int j = 0; j < NBLK; ++j) {
        while (iload(&done[j]) != DONE_MAGIC) __builtin_amdgcn_s_sleep(1);
        lp += fload(&part[2 * j]);
        en += fload(&part[2 * j + 1]);
      }
      out[60] = lp;
      out[61] = en;
    }
  }
}

extern "C" void kernel_launch(void* const* d_in, const int* in_sizes, int n_in,
                              void* d_out, int out_size, void* d_ws, size_t ws_size,
                              hipStream_t stream) {
  const float* enc = (const float*)d_in[0];
  const float* wih = (const float*)d_in[1];
  const float* whh = (const float*)d_in[2];
  const float* bih = (const float*)d_in[3];
  const float* bhh = (const float*)d_in[4];
  const float* w1  = (const float*)d_in[5];
  const float* w2  = (const float*)d_in[6];
  const float* v   = (const float*)d_in[7];
  unsigned char* ws = (unsigned char*)d_ws;
  float* out = (float*)d_out;

  if (ws_size >= V10_NEED) {
    ctrl_v10<<<dim3(64), dim3(1024), 0, stream>>>(
        enc, wih, whh, bih, bhh, w1, w2, v, ws, out);
  } else {
    ctrl_small<<<dim3(64), dim3(1024), 0, stream>>>(
        enc, wih, whh, bih, bhh, w1, w2, v, ws, out);
  }
}

// Round 11
// 152.379 us; speedup vs baseline: 1.0391x; 1.0391x over previous
//
#include <hip/hip_runtime.h>
#include <stdint.h>

// ENAS LSTM controller. R11: 512-thread wgs + centralized sampling.
//  - R10 evidence: VGPR_Count=64 (< the 80+ needed) -> weights were NOT
//    register-resident (1024-thr wgs cap VGPRs at 128); FETCH 10.6MB = ~4x
//    weight refetch. Now 512 thr + __launch_bounds__(512,2) -> 256-VGPR
//    budget; each thread holds 128 VGPRs of wih/whh rows + 32 of w1/w2 cols.
//  - Exchange cost scales with sc1 word count (R7 40w/4.1us vs R10 2300w/
//    6.2us). Only wg p=0 samples now: peers poll 256 tagged h words + ONE
//    index word; y-partials go to a packed (2 floats/u64) mailbox read only
//    by wg0 (8 tag words polled, 1024 words read once). Peers overlap their
//    index wait with the stashed dotHH (index-independent).
//  - h exchange: R10's proven self-validating tagged words, 2-slot rotation.
//    y mailbox 2-slot; reuse safe: y_k+2 writes happen after h_k+1 was
//    observed, which wg0 published only after finishing its y_k reads.
//  - ws need 126,976 B (proven >= 221,696 since ctrl_v10 ran); R8-style
//    fallback kept for safety.

#define NBLK  6
#define PWG   8
#define THR   512
#define TINYF 1.17549435e-38f
#define HTAGB 0xC3B00000u
#define YTAGB 0xE1700000u
#define ITAGB 0xA5D00000u
#define DONE_MAGIC 0x444f4e45

typedef unsigned long long u64;
struct U2 { uint32_t x, y; };

// ---- v11 ws layout (bytes) ----
#define W_DONE 0u        // int[8]
#define W_PART 64u       // float[12]
#define W_IDX  128u      // u64[6][10] = 480
#define W_HX   640u      // u64[2][6][256] = 24576
#define W_YMB  25216u    // u64[2][6][8][129] = 99072
#define W_NEED 126976u

// ---- fallback (R8/R10 small) ws layout ----
#define S_READY 0u
#define S_DONE  192u
#define S_PART  224u
#define S_HP    320u
#define S_ACC   24896u
#define FXS     67108864.0f
#define READY_MAGIC 0x52454459

// Threefry-2x32, 20 rounds (Random123 / JAX). Key (k0,k1), counter (c0,c1).
__device__ __forceinline__ U2 tf2x32(uint32_t k0, uint32_t k1,
                                     uint32_t c0, uint32_t c1) {
  uint32_t ks2 = k0 ^ k1 ^ 0x1BD11BDAu;
  uint32_t x0 = c0 + k0, x1 = c1 + k1;
#define TFR(r) { x0 += x1; x1 = (x1 << (r)) | (x1 >> (32 - (r))); x1 ^= x0; }
  TFR(13) TFR(15) TFR(26) TFR(6)   x0 += k1;  x1 += ks2 + 1u;
  TFR(17) TFR(29) TFR(16) TFR(24)  x0 += ks2; x1 += k0 + 2u;
  TFR(13) TFR(15) TFR(26) TFR(6)   x0 += k0;  x1 += k1 + 3u;
  TFR(17) TFR(29) TFR(16) TFR(24)  x0 += k1;  x1 += ks2 + 4u;
  TFR(13) TFR(15) TFR(26) TFR(6)   x0 += ks2; x1 += k0 + 5u;
#undef TFR
  U2 r; r.x = x0; r.y = x1; return r;
}

__device__ __forceinline__ float sigf(float x) {
  return 1.0f / (1.0f + expf(-x));
}
// relaxed agent-scope (LLC-resolved) accessors -- the only sync primitives.
__device__ __forceinline__ void istore(int* p, int v) {
  __hip_atomic_store(p, v, __ATOMIC_RELAXED, __HIP_MEMORY_SCOPE_AGENT);
}
__device__ __forceinline__ int iload(const int* p) {
  return __hip_atomic_load(p, __ATOMIC_RELAXED, __HIP_MEMORY_SCOPE_AGENT);
}
__device__ __forceinline__ void hstore(u64* p, u64 v) {
  __hip_atomic_store(p, v, __ATOMIC_RELAXED, __HIP_MEMORY_SCOPE_AGENT);
}
__device__ __forceinline__ u64 hload(const u64* p) {
  return __hip_atomic_load(p, __ATOMIC_RELAXED, __HIP_MEMORY_SCOPE_AGENT);
}
__device__ __forceinline__ void fstore(float* p, float v) {
  __hip_atomic_store(p, v, __ATOMIC_RELAXED, __HIP_MEMORY_SCOPE_AGENT);
}
__device__ __forceinline__ float fload(const float* p) {
  return __hip_atomic_load(p, __ATOMIC_RELAXED, __HIP_MEMORY_SCOPE_AGENT);
}
__device__ __forceinline__ u64 pollw(const u64* p, uint32_t want) {
  u64 v;
  for (;;) {
    v = hload(p);
    if ((uint32_t)(v >> 32) == want) return v;
    __builtin_amdgcn_s_sleep(1);
  }
}

// =================== R11 kernel ============================================
__global__ __launch_bounds__(THR, 2) void ctrl_v11(
    const float* __restrict__ enc_w,
    const float* __restrict__ wih,
    const float* __restrict__ whh,
    const float* __restrict__ b_ih,
    const float* __restrict__ b_hh,
    const float* __restrict__ w1,
    const float* __restrict__ w2,
    const float* __restrict__ vvec,
    unsigned char* __restrict__ ws,
    float* __restrict__ out) {

  const int b = blockIdx.x & 7;      // XCD swizzle: chain b -> XCD b (if RR)
  const int p = blockIdx.x >> 3;
  if (b >= NBLK) return;
  const int tid = threadIdx.x;

  int*   done = (int*)(ws + W_DONE);
  float* part = (float*)(ws + W_PART);
  u64*   idxw = (u64*)(ws + W_IDX);
  u64*   hx   = (u64*)(ws + W_HX);    // [2][6][256]
  u64*   ymb  = (u64*)(ws + W_YMB);   // [2][6][8][129] (128 data + tag)

  // gate GEMV: 128 local rows x 4 k-slices of 64 (s wave-uniform -> LDS bcast)
  const int rl = tid & 127, s = tid >> 7;
  const int grow = (rl >> 5) * 256 + p * 32 + (rl & 31);
  const int k0 = s * 64;
  // y-partial: element rr, col half ks (cols p*32 + ks*16 + j)
  const int rr = tid & 255, ks = tid >> 8;
  const int cb = p * 32 + ks * 16;

  __shared__ __align__(16) float gateL[THR];
  __shared__ __align__(16) float hL[256], encL[256], vL[256];
  __shared__ __align__(16) float anchL[4][256];
  __shared__ __align__(16) float w2hS[256], aw1S[6][256];
  __shared__ __align__(16) float yL8[8][256];
  __shared__ float rowSumL[128], biasS[128], h2S[32];
  __shared__ float logitL[8];
  __shared__ int   selL;

  if (tid < 256) { encL[tid] = enc_w[tid]; vL[tid] = vvec[tid]; }
  if (tid < 128) {
    int r = (tid >> 5) * 256 + p * 32 + (tid & 31);
    biasS[tid] = b_ih[r] + b_hh[r];
  }

  // register-resident weights (fits the 256-VGPR budget of 512-thr wgs)
  float4 wihr[16], whhr[16];
  #pragma unroll
  for (int c = 0; c < 16; ++c) {
    wihr[c] = *(const float4*)(wih + grow * 256 + k0 + c * 4);
    whhr[c] = *(const float4*)(whh + grow * 256 + k0 + c * 4);
  }
  float w1c[16], w2c[16];
  #pragma unroll
  for (int j = 0; j < 16; ++j) {
    w1c[j] = w1[rr * 256 + cb + j];
    w2c[j] = w2[rr * 256 + cb + j];
  }
  __syncthreads();

  auto dotIH = [&](const float* x) {
    float a = 0.0f;
    #pragma unroll
    for (int c = 0; c < 16; ++c) {
      float4 xv = *(const float4*)(x + k0 + c * 4);
      float4 w = wihr[c];
      a += w.x * xv.x + w.y * xv.y + w.z * xv.z + w.w * xv.w;
    }
    return a;
  };
  auto dotHH = [&]() {
    float a = 0.0f;
    #pragma unroll
    for (int c = 0; c < 16; ++c) {
      float4 xv = *(const float4*)(hL + k0 + c * 4);
      float4 w = whhr[c];
      a += w.x * xv.x + w.y * xv.y + w.z * xv.z + w.w * xv.w;
    }
    return a;
  };

  const float encih = dotIH(encL);   // wih @ enc, reused by all enc cells

  float cv = 0.0f;                            // c for element p*32+tid (tid<32)
  U2 bk = tf2x32(0u, 42u, 0u, (uint32_t)b);   // fold_in(key(42), b)
  int k = 1, step = 0;
  float lpAcc = 0.0f, entAcc = 0.0f;

  // One cell + exchange. mode 0: y = w2 partial (sample next);
  // mode 1: y = w1 partial -> wg0 aw1S[aid] (+ anchor -> anchL[cid] all wgs);
  // mode 2: last cell (no exchange).
  auto cell = [&](float gacc, int mode, int aid, int cid) {
    gateL[tid] = gacc;                       // tid = s*128 + rl
    __syncthreads();
    if (tid < 128) {
      float ssum = 0.0f;
      #pragma unroll
      for (int j = 0; j < 4; ++j) ssum += gateL[j * 128 + tid];
      rowSumL[tid] = ssum + biasS[tid];
    }
    __syncthreads();
    if (tid < 32) {
      float gi = rowSumL[tid],       gf = rowSumL[32 + tid];
      float gg2 = rowSumL[64 + tid], go = rowSumL[96 + tid];
      float c2 = sigf(gf) * cv + sigf(gi) * tanhf(gg2);
      float h2 = sigf(go) * tanhf(c2);
      cv = c2;
      h2S[tid] = h2;
      if (mode == 2) {
        if (b == NBLK - 1) { out[62 + p * 32 + tid] = cv; out[318 + p * 32 + tid] = h2; }
      } else {                               // publish own h ASAP (tagged)
        hstore(&hx[(k & 1) * 1536 + b * 256 + p * 32 + tid],
               ((u64)(HTAGB | (uint32_t)k) << 32) | (u64)__float_as_uint(h2));
      }
    }
    __syncthreads();                         // h2S visible
    if (mode == 2) return;

    {                                        // own y partial (16 cols)
      const float* wc = (mode == 1) ? w1c : w2c;
      float yp = 0.0f;
      #pragma unroll
      for (int j = 0; j < 16; ++j) yp += wc[j] * h2S[ks * 16 + j];
      gateL[tid] = yp;                       // layout ks*256 + rr
    }
    __syncthreads();
    u64* mslot = ymb + (size_t)(k & 1) * 6192 + (b * 8 + p) * 129;
    if (tid < 128) {                         // pack 2 col-summed floats/u64
      float ya = gateL[2 * tid]     + gateL[256 + 2 * tid];
      float yb = gateL[2 * tid + 1] + gateL[256 + 2 * tid + 1];
      hstore(mslot + tid,
             ((u64)__float_as_uint(yb) << 32) | (u64)__float_as_uint(ya));
    }
    __syncthreads();                         // drain y data before tag
    if (tid == 0)
      hstore(mslot + 128, ((u64)(YTAGB | (uint32_t)k) << 32) | 1u);

    // consume: poll full h (all wgs)
    if (tid < 256) {
      u64 v = pollw(&hx[(k & 1) * 1536 + b * 256 + tid], HTAGB | (uint32_t)k);
      float hv = __uint_as_float((uint32_t)v);
      hL[tid] = hv;
      if (mode == 1 && cid >= 0) anchL[cid][tid] = hv;
    }
    __syncthreads();

    if (p == 0) {                            // wg0: gather y mailbox
      if (tid < 8)
        pollw(ymb + (size_t)(k & 1) * 6192 + (b * 8 + tid) * 129 + 128,
              YTAGB | (uint32_t)k);
      __syncthreads();
      {
        int pw = tid >> 6, o = tid & 63;
        const u64* mb = ymb + (size_t)(k & 1) * 6192 + (b * 8 + pw) * 129;
        u64 wa = hload(mb + 2 * o), wb = hload(mb + 2 * o + 1);
        yL8[pw][4 * o + 0] = __uint_as_float((uint32_t)wa);
        yL8[pw][4 * o + 1] = __uint_as_float((uint32_t)(wa >> 32));
        yL8[pw][4 * o + 2] = __uint_as_float((uint32_t)wb);
        yL8[pw][4 * o + 3] = __uint_as_float((uint32_t)(wb >> 32));
      }
      __syncthreads();
      if (tid < 256) {
        float y = 0.0f;
        #pragma unroll
        for (int pw = 0; pw < 8; ++pw) y += yL8[pw][tid];
        if (mode == 1) aw1S[aid][tid] = y; else w2hS[tid] = y;
      }
      __syncthreads();
    }
    ++k;
  };

  // wg0 samples; peers poll the broadcast index word.
  auto resolve = [&](int L) -> int {
    if (p == 0) {
      int wv = tid >> 6, lane = tid & 63;
      if (wv < L) {
        float a = 0.0f;
        #pragma unroll
        for (int j = 0; j < 4; ++j) {        // stride-64: conflict-free
          int kk = j * 64 + lane;
          a += tanhf(aw1S[wv][kk] + w2hS[kk]) * vL[kk];
        }
        a += __shfl_down(a, 32);
        a += __shfl_down(a, 16);
        a += __shfl_down(a, 8);
        a += __shfl_down(a, 4);
        a += __shfl_down(a, 2);
        a += __shfl_down(a, 1);
        if (lane == 0) logitL[wv] = a;
      }
      __syncthreads();
      if (tid < 64) {                        // wave 0: selection (R10 math)
        float lg = 0.0f, sgum = -1e30f;
        if (tid < L) {
          lg = 1.1f * tanhf(logitL[tid] * 0.2f);
          U2 sk = tf2x32(bk.x, bk.y, 0u, (uint32_t)step);
          U2 r2 = tf2x32(sk.x, sk.y, 0u, (uint32_t)tid);
          uint32_t bits = r2.x ^ r2.y;
          float u = __uint_as_float((bits >> 9) | 0x3f800000u) - 1.0f;
          u = fmaxf(TINYF, u + TINYF);       // jax uniform(tiny, 1)
          sgum = lg - logf(-logf(u));
        }
        int bi = 0;
        float best = __shfl(sgum, 0, 64);
        for (int j = 1; j < L; ++j) {
          float sj = __shfl(sgum, j, 64);
          if (sj > best) { best = sj; bi = j; }   // first-max = jnp.argmax
        }
        float mx = __shfl(lg, 0, 64);
        for (int j = 1; j < L; ++j) mx = fmaxf(mx, __shfl(lg, j, 64));
        float se = 0.0f;
        for (int j = 0; j < L; ++j) se += expf(__shfl(lg, j, 64) - mx);
        float lse = logf(se);
        float lgbi = __shfl(lg, bi, 64);
        float es = 0.0f;
        for (int j = 0; j < L; ++j) {
          float l = __shfl(lg, j, 64) - mx - lse;
          es += l * expf(l);
        }
        if (tid == 0) {
          lpAcc += -(lgbi - mx - lse);
          entAcc += -es;
          selL = bi;
          out[b * 10 + step] = (float)bi;
          hstore(&idxw[b * 10 + step],
                 ((u64)(ITAGB | (uint32_t)step) << 32) | (u64)(uint32_t)bi);
        }
      }
      __syncthreads();
    } else {
      if (tid == 0) {
        u64 v = pollw(&idxw[b * 10 + step], ITAGB | (uint32_t)step);
        selL = (int)(uint32_t)v;
      }
      __syncthreads();
    }
    step++;
    return selL;
  };

  // ---- chain ----
  cell(encih, 1, 0, -1);             // zero-state cell; wg0 gets aw1[0]
  if (p == 0) {
    if (tid < 256) aw1S[1][tid] = aw1S[0][tid];
    __syncthreads();
  }

  for (int L = 2; L <= 6; ++L) {
    { float hh = dotHH(); cell(encih + hh, 0, 0, -1); }          // cellA
    {
      int s1; float hh;
      if (p == 0) { s1 = resolve(L); hh = dotHH(); }             // idx ASAP
      else        { hh = dotHH(); s1 = resolve(L); }             // overlap wait
      float a = (s1 >= 2) ? dotIH(&anchL[s1 - 2][0]) : 0.0f;
      cell(a + hh, 0, 0, -1);                                    // cellB
    }
    {
      int s2; float hh;
      if (p == 0) { s2 = resolve(L); hh = dotHH(); }
      else        { hh = dotHH(); s2 = resolve(L); }
      float a = (s2 >= 2) ? dotIH(&anchL[s2 - 2][0]) : 0.0f;
      if (L < 6) cell(a + hh, 1, L, L - 2);                      // cellC anchor
      else       cell(a + hh, 2, 0, -1);                         // last cell
    }
  }

  if (p == 0 && tid == 0) {
    fstore(&part[2 * b], lpAcc);
    fstore(&part[2 * b + 1], entAcc);
    __builtin_amdgcn_s_waitcnt(0);
    istore(&done[b], DONE_MAGIC);
    if (b == NBLK - 1) {
      float lp = 0.0f, en = 0.0f;
      for (int j = 0; j < NBLK; ++j) {
        while (iload(&done[j]) != DONE_MAGIC) __builtin_amdgcn_s_sleep(1);
        lp += fload(&part[2 * j]);
        en += fload(&part[2 * j + 1]);
      }
      out[60] = lp;
      out[61] = en;
    }
  }
}

// =================== fallback (proven R8-style; small ws) ==================
__global__ __launch_bounds__(1024) void ctrl_small(
    const float* __restrict__ enc_w,
    const float* __restrict__ wih,
    const float* __restrict__ whh,
    const float* __restrict__ b_ih,
    const float* __restrict__ b_hh,
    const float* __restrict__ w1,
    const float* __restrict__ w2,
    const float* __restrict__ vvec,
    unsigned char* __restrict__ ws,
    float* __restrict__ out) {

  const int b = blockIdx.x & 7;
  const int p = blockIdx.x >> 3;
  if (b >= NBLK) return;
  const int tid = threadIdx.x;

  int*   ready = (int*)(ws + S_READY);
  int*   done  = (int*)(ws + S_DONE);
  float* part  = (float*)(ws + S_PART);
  u64*   hp    = (u64*)(ws + S_HP);
  int*   acc   = (int*)(ws + S_ACC);

  const int rl = tid >> 3, s = tid & 7;
  const int g = rl >> 5, el = rl & 31;
  const int row = g * 256 + p * 32 + el;
  const int k0 = s * 32;
  const int rr = tid & 255, ks = tid >> 8;

  __shared__ __align__(16) float hL[256], encL[256], vL[256];
  __shared__ __align__(16) float anchL[4][256];
  __shared__ __align__(16) float partL[1024];
  __shared__ __align__(16) float w2hS[256], aw1S[6][256];
  __shared__ float rowSumL[128], biasS[128], h2S[32];
  __shared__ float logitL[8];
  __shared__ int   selL;

  if (tid < 256) { encL[tid] = enc_w[tid]; vL[tid] = vvec[tid]; }
  if (tid < 128) {
    int gg = tid >> 5, ee = tid & 31, r = gg * 256 + p * 32 + ee;
    biasS[tid] = b_ih[r] + b_hh[r];
  }

  float4 wihr[8], whhr[8];
  #pragma unroll
  for (int c = 0; c < 8; ++c) {
    int cc = (c + s) & 7;
    wihr[c] = *(const float4*)(wih + row * 256 + k0 + cc * 4);
    whhr[c] = *(const float4*)(whh + row * 256 + k0 + cc * 4);
  }
  float w1c[8], w2c[8];
  #pragma unroll
  for (int j = 0; j < 8; ++j) {
    w1c[j] = w1[rr * 256 + p * 32 + ks * 8 + j];
    w2c[j] = w2[rr * 256 + p * 32 + ks * 8 + j];
  }

  if (tid < 32) istore(&acc[1 * (NBLK * 256) + b * 256 + p * 32 + tid], 0);
  __syncthreads();
  if (tid == 0) istore(&ready[b * 8 + p], READY_MAGIC);
  if (tid < 8) {
    while (iload(&ready[b * 8 + tid]) != READY_MAGIC)
      __builtin_amdgcn_s_sleep(1);
  }
  __syncthreads();

  auto dotIH = [&](const float* x) {
    float a = 0.0f;
    #pragma unroll
    for (int c = 0; c < 8; ++c) {
      int cc = (c + s) & 7;
      float4 xv = *(const float4*)(x + k0 + cc * 4);
      float4 w = wihr[c];
      a += w.x * xv.x + w.y * xv.y + w.z * xv.z + w.w * xv.w;
    }
    return a;
  };
  auto dotHH = [&]() {
    float a = 0.0f;
    #pragma unroll
    for (int c = 0; c < 8; ++c) {
      int cc = (c + s) & 7;
      float4 xv = *(const float4*)(hL + k0 + cc * 4);
      float4 w = whhr[c];
      a += w.x * xv.x + w.y * xv.y + w.z * xv.z + w.w * xv.w;
    }
    return a;
  };

  const float encih = dotIH(encL);
  float cv = 0.0f;
  U2 bk = tf2x32(0u, 42u, 0u, (uint32_t)b);
  int k = 1, step = 0;
  float lpAcc = 0.0f, entAcc = 0.0f;

  auto cell = [&](float gacc, int mode, int aid, int cid) {
    partL[tid] = gacc;
    __syncthreads();
    if (tid < 128) {
      float ssum = 0.0f;
      #pragma unroll
      for (int j = 0; j < 8; ++j) ssum += partL[tid * 8 + j];
      rowSumL[tid] = ssum + biasS[tid];
    }
    __syncthreads();
    if (tid < 32) {
      float gi = rowSumL[tid],       gf = rowSumL[32 + tid];
      float gg2 = rowSumL[64 + tid], go = rowSumL[96 + tid];
      float c2 = sigf(gf) * cv + sigf(gi) * tanhf(gg2);
      float h2 = sigf(go) * tanhf(c2);
      cv = c2;
      h2S[tid] = h2;
      if (mode == 2 && b == NBLK - 1) {
        out[62 + p * 32 + tid] = cv;
        out[318 + p * 32 + tid] = h2;
      }
    }
    __syncthreads();
    if (mode == 2) return;
    {
      const float* wc = (mode == 1) ? w1c : w2c;
      float yp = 0.0f;
      #pragma unroll
      for (int j = 0; j < 8; ++j) yp += wc[j] * h2S[ks * 8 + j];
      atomicAdd(&acc[(k % 3) * (NBLK * 256) + b * 256 + rr],
                __float2int_rn(yp * FXS));
      if (tid < 32)
        istore(&acc[((k + 1) % 3) * (NBLK * 256) + b * 256 + p * 32 + tid], 0);
    }
    __syncthreads();
    if (tid < 32) {
      u64 pk = ((u64)(uint32_t)k << 32) | (u64)__float_as_uint(h2S[tid]);
      hstore(&hp[(k & 1) * (NBLK * 256) + b * 256 + p * 32 + tid], pk);
    }
    if (tid < 256) {
      u64 v;
      const u64* src = &hp[(k & 1) * (NBLK * 256) + b * 256 + tid];
      while ((int)(hload(src) >> 32) != k) __builtin_amdgcn_s_sleep(1);
      v = hload(src);
      float hv = __uint_as_float((uint32_t)v);
      hL[tid] = hv;
      if (mode == 1 && cid >= 0) anchL[cid][tid] = hv;
    }
    __syncthreads();
    if (tid < 256) {
      int iv = iload(&acc[(k % 3) * (NBLK * 256) + b * 256 + tid]);
      float f = (float)((double)iv * (1.0 / 67108864.0));
      if (mode == 1) aw1S[aid][tid] = f; else w2hS[tid] = f;
    }
    __syncthreads();
    ++k;
  };

  auto sample = [&](int L) -> int {
    int wv = tid >> 6, lane = tid & 63;
    if (wv < L) {
      float a = 0.0f;
      #pragma unroll
      for (int j = 0; j < 4; ++j) {
        int kk = lane * 4 + j;
        a += tanhf(aw1S[wv][kk] + w2hS[kk]) * vL[kk];
      }
      a += __shfl_down(a, 32);
      a += __shfl_down(a, 16);
      a += __shfl_down(a, 8);
      a += __shfl_down(a, 4);
      a += __shfl_down(a, 2);
      a += __shfl_down(a, 1);
      if (lane == 0) logitL[wv] = a;
    }
    __syncthreads();
    if (tid < 64) {
      float lg = 0.0f, sgum = -1e30f;
      if (tid < L) {
        lg = 1.1f * tanhf(logitL[tid] * 0.2f);
        U2 sk = tf2x32(bk.x, bk.y, 0u, (uint32_t)step);
        U2 r2 = tf2x32(sk.x, sk.y, 0u, (uint32_t)tid);
        uint32_t bits = r2.x ^ r2.y;
        float u = __uint_as_float((bits >> 9) | 0x3f800000u) - 1.0f;
        u = fmaxf(TINYF, u + TINYF);
        sgum = lg - logf(-logf(u));
      }
      int bi = 0;
      float best = __shfl(sgum, 0, 64);
      for (int j = 1; j < L; ++j) {
        float sj = __shfl(sgum, j, 64);
        if (sj > best) { best = sj; bi = j; }
      }
      float mx = __shfl(lg, 0, 64);
      for (int j = 1; j < L; ++j) mx = fmaxf(mx, __shfl(lg, j, 64));
      float se = 0.0f;
      for (int j = 0; j < L; ++j) se += expf(__shfl(lg, j, 64) - mx);
      float lse = logf(se);
      float lgbi = __shfl(lg, bi, 64);
      float es = 0.0f;
      for (int j = 0; j < L; ++j) {
        float l = __shfl(lg, j, 64) - mx - lse;
        es += l * expf(l);
      }
      if (tid == 0) {
        lpAcc += -(lgbi - mx - lse);
        entAcc += -es;
        selL = bi;
        if (p == 0) out[b * 10 + step] = (float)bi;
      }
    }
    __syncthreads();
    step++;
    return selL;
  };

  cell(encih, 1, 0, -1);
  if (tid < 256) aw1S[1][tid] = aw1S[0][tid];
  __syncthreads();
  for (int L = 2; L <= 6; ++L) {
    cell(encih + dotHH(), 0, 0, -1);
    int s1v = sample(L);
    {
      float a = (s1v >= 2) ? dotIH(&anchL[s1v - 2][0]) : 0.0f;
      cell(a + dotHH(), 0, 0, -1);
    }
    int s2v = sample(L);
    {
      float a = (s2v >= 2) ? dotIH(&anchL[s2v - 2][0]) : 0.0f;
      if (L < 6) cell(a + dotHH(), 1, L, L - 2);
      else       cell(a + dotHH(), 2, 0, -1);
    }
  }
  if (p == 0 && tid == 0) {
    fstore(&part[2 * b], lpAcc);
    fstore(&part[2 * b + 1], entAcc);
    __builtin_amdgcn_s_waitcnt(0);
    istore(&done[b], DONE_MAGIC);
    if (b == NBLK - 1) {
      float lp = 0.0f, en = 0.0f;
      for (int j = 0; j < NBLK; ++j) {
        while (iload(&done[j]) != DONE_MAGIC) __builtin_amdgcn_s_sleep(1);
        lp += fload(&part[2 * j]);
        en += fload(&part[2 * j + 1]);
      }
      out[60] = lp;
      out[61] = en;
    }
  }
}

extern "C" void kernel_launch(void* const* d_in, const int* in_sizes, int n_in,
                              void* d_out, int out_size, void* d_ws, size_t ws_size,
                              hipStream_t stream) {
  const float* enc = (const float*)d_in[0];
  const float* wih = (const float*)d_in[1];
  const float* whh = (const float*)d_in[2];
  const float* bih = (const float*)d_in[3];
  const float* bhh = (const float*)d_in[4];
  const float* w1  = (const float*)d_in[5];
  const float* w2  = (const float*)d_in[6];
  const float* v   = (const float*)d_in[7];
  unsigned char* ws = (unsigned char*)d_ws;
  float* out = (float*)d_out;

  if (ws_size >= W_NEED) {
    ctrl_v11<<<dim3(64), dim3(THR), 0, stream>>>(
        enc, wih, whh, bih, bhh, w1, w2, v, ws, out);
  } else {
    ctrl_small<<<dim3(64), dim3(1024), 0, stream>>>(
        enc, wih, whh, bih, bhh, w1, w2, v, ws, out);
  }
}